// Round 6
// baseline (157.961 us; speedup 1.0000x reference)
//
#include <hip/hip_runtime.h>
#include <hip/hip_bf16.h>

#define B_   8
#define N_   512
#define IND  256
#define H_   4
#define PH   32
#define OD   128   // H_*PH
#define TI   4     // targets per block (attn)
#define TJ   64    // source tile (attn)

typedef float v2f __attribute__((ext_vector_type(2)));

__device__ __forceinline__ float dpp_xor1_add(float x) {
    // x + (lane^1)'s x via quad_perm(1,0,3,2) -- VALU DPP, no LDS pipe.
    int yi = __builtin_amdgcn_mov_dpp(__float_as_int(x), 0xB1, 0xF, 0xF, true);
    return x + __int_as_float(yi);
}

__device__ __forceinline__ void async_copy16(void* lds_base_uniform, const void* g_perlane) {
    // HW writes lds[base + lane*16]; lds arg must be the wave-uniform base.
    __builtin_amdgcn_global_load_lds(
        (const __attribute__((address_space(1))) unsigned*)g_perlane,
        (__attribute__((address_space(3))) unsigned*)lds_base_uniform,
        16, 0, 0);
}

// ---------------------------------------------------------------------------
// Kernel 1: xl = x@Wl + bl ; xr = x@Wr + br  plus fused rank-1 parts
//   dl[n,h] = sum_c att[h,c]*xl[n,h,c], dr likewise (att dot per head).
// grid 512, block 256; 8 rows per block. (unchanged from round 5)
// ---------------------------------------------------------------------------
__global__ __launch_bounds__(256, 2) void proj_kernel(
    const float* __restrict__ x,
    const float* __restrict__ Wl, const float* __restrict__ bl,
    const float* __restrict__ Wr, const float* __restrict__ br,
    const float* __restrict__ att,
    float* __restrict__ xl, float* __restrict__ xr,
    float* __restrict__ dl, float* __restrict__ dr)
{
    __shared__ float xs[8 * IND];
    const int t = threadIdx.x;
    const int row0 = blockIdx.x * 8;

    const float4* xp4 = (const float4*)(x + (size_t)row0 * IND);
    float4* xs4 = (float4*)xs;
    #pragma unroll
    for (int k = 0; k < 2; ++k)
        xs4[t + k * 256] = xp4[t + k * 256];
    __syncthreads();

    const int which = t >> 7;
    const int rg = (t >> 6) & 1;
    const int og = t & 63;
    const int o0 = og * 2;
    const int r0 = rg * 4;
    const float* W  = which ? Wr : Wl;
    const float* bb = which ? br : bl;

    float acc0[4], acc1[4];
    #pragma unroll
    for (int r = 0; r < 4; ++r) { acc0[r] = 0.f; acc1[r] = 0.f; }

    for (int k = 0; k < IND; k += 4) {
        float wf0[4], wf1[4];
        #pragma unroll
        for (int kk = 0; kk < 4; ++kk) {
            float2 wv = *(const float2*)(W + (size_t)(k + kk) * OD + o0);
            wf0[kk] = wv.x;
            wf1[kk] = wv.y;
        }
        float xv[4][4];
        #pragma unroll
        for (int r = 0; r < 4; ++r)
            *(float4*)(xv[r]) = *(const float4*)(&xs[(r0 + r) * IND + k]);
        #pragma unroll
        for (int kk = 0; kk < 4; ++kk)
            #pragma unroll
            for (int r = 0; r < 4; ++r) {
                acc0[r] = fmaf(xv[r][kk], wf0[kk], acc0[r]);
                acc1[r] = fmaf(xv[r][kk], wf1[kk], acc1[r]);
            }
    }

    const float bv0 = bb[o0];
    const float bv1 = bb[o0 + 1];
    const float a0 = att[o0];
    const float a1 = att[o0 + 1];
    float* dst = which ? xr : xl;
    float* dp  = which ? dr : dl;
    float dcon[4];
    #pragma unroll
    for (int r = 0; r < 4; ++r) {
        float y0 = acc0[r] + bv0;
        float y1 = acc1[r] + bv1;
        *(float2*)(&dst[(size_t)(row0 + r0 + r) * OD + o0]) = make_float2(y0, y1);
        dcon[r] = fmaf(a0, y0, a1 * y1);
    }
    #pragma unroll
    for (int m = 1; m < 16; m <<= 1) {
        #pragma unroll
        for (int r = 0; r < 4; ++r)
            dcon[r] += __shfl_xor(dcon[r], m);
    }
    if ((og & 15) == 0) {
        const int h = og >> 4;
        #pragma unroll
        for (int r = 0; r < 4; ++r)
            dp[(size_t)(row0 + r0 + r) * H_ + h] = dcon[r];
    }
}

// ---------------------------------------------------------------------------
// Kernel 2: masked-softmax attention aggregate.
// grid 1024 (= B*N/TI), block 256, LDS 33 KB -> 4 blocks/CU.
// thread: ch = t&1 (c-half), il = (t>>1)&3 (target), q = (t>>3)&7 (j-slice),
//         h = t>>6 (head == wave).
// Cluster (8 lanes) = {ch,il} with jj fixed -> LDS v-reads are 4-lane
// broadcasts at 2 distinct bank groups: conflict-free at stride 128 (no pad),
// which lets staging use global_load_lds width=16 (lane-contiguous layout).
// e2 pair-combine via DPP quad_perm (VALU) -- round-5's per-u ds_bpermute
// was the latency/conflict source. Packed v_pk_* math via float2 vectors.
// e = 0.6(dr+dl) + sum_c (0.4*att_c)*|xr_c+xl_c|; softmax w/o max-sub.
// ---------------------------------------------------------------------------
__global__ __launch_bounds__(256) void attn_kernel(
    const int* __restrict__ adj, const float* __restrict__ att,
    const float* __restrict__ bias,
    const float* __restrict__ xl, const float* __restrict__ xr,
    const float* __restrict__ dl, const float* __restrict__ dr,
    float* __restrict__ out)
{
    __shared__ float xls[TJ * OD];    // 32 KB, stride 128 (lane-contiguous)
    __shared__ float masks[TJ * TI];  // 1 KB   [jj][il]

    const int t = threadIdx.x;
    const int b  = blockIdx.x >> 7;
    const int i0 = (blockIdx.x & 127) * TI;
    const int ch = t & 1;
    const int il = (t >> 1) & 3;
    const int q  = (t >> 3) & 7;
    const int h  = t >> 6;
    const int lane = t & 63;
    const int wv = __builtin_amdgcn_readfirstlane(t >> 6);
    const int ig = i0 + il;
    const int cbase = h * PH + ch * 16;

    v2f attv[8], xrv[8];
    {
        const float* xrp = xr + ((size_t)(b * N_ + ig)) * OD + cbase;
        const float* ap  = att + cbase;
        #pragma unroll
        for (int k = 0; k < 4; ++k) {
            float4 v = *(const float4*)(xrp + k * 4);
            xrv[2*k]   = (v2f){v.x, v.y};
            xrv[2*k+1] = (v2f){v.z, v.w};
            float4 a = *(const float4*)(ap + k * 4);
            attv[2*k]   = (v2f){0.4f * a.x, 0.4f * a.y};   // fold leaky 0.4
            attv[2*k+1] = (v2f){0.4f * a.z, 0.4f * a.w};
        }
    }
    const float c0 = 0.6f * dr[((size_t)(b * N_ + ig)) * H_ + h];

    v2f acc2[8];
    #pragma unroll
    for (int m = 0; m < 8; ++m) acc2[m] = (v2f){0.f, 0.f};
    float sumw = 0.f;

    const float* xlb = xl + (size_t)b * N_ * OD;
    const int* adjb  = adj + (size_t)b * N_ * N_;

    for (int tile = 0; tile < N_ / TJ; ++tile) {
        const int j0 = tile * TJ;
        __syncthreads();
        // async global->LDS staging: 8 x 1KB per wave, lane-contiguous.
        {
            const float* gsrc = xlb + (size_t)j0 * OD;
            #pragma unroll
            for (int k = 0; k < 8; ++k) {
                const int base4 = k * 256 + wv * 64;   // float4 units, uniform
                async_copy16(&xls[base4 * 4], gsrc + (size_t)(base4 + lane) * 4);
            }
        }
        // adjacency mask: m[i,j] = adj[b][j][i] != 0, diagonal forced 1
        {
            int jj = t >> 2, ii = t & 3;
            int jg2 = j0 + jj, ig2 = i0 + ii;
            int a = adjb[(size_t)jg2 * N_ + ig2];
            masks[t] = (a != 0 || jg2 == ig2) ? 1.f : 0.f;
        }
        __syncthreads();   // drains vmcnt (async LDS) + masks writes

        // per-u logit bases from precomputed dl (L2-hot scalar loads)
        const float* dlt = dl + ((size_t)b * N_ + j0) * H_ + h;
        float ebase[8];
        #pragma unroll
        for (int u = 0; u < 8; ++u)
            ebase[u] = fmaf(0.6f, dlt[(q + u * 8) * H_], c0);

        #pragma unroll
        for (int u = 0; u < 8; ++u) {
            const int jj = q + u * 8;
            const float* vrow = &xls[jj * OD + cbase];
            float4 f0 = *(const float4*)(vrow + 0);
            float4 f1 = *(const float4*)(vrow + 4);
            float4 f2 = *(const float4*)(vrow + 8);
            float4 f3 = *(const float4*)(vrow + 12);
            v2f vv[8] = {{f0.x,f0.y},{f0.z,f0.w},{f1.x,f1.y},{f1.z,f1.w},
                         {f2.x,f2.y},{f2.z,f2.w},{f3.x,f3.y},{f3.z,f3.w}};
            v2f e2a = (v2f){0.f, 0.f}, e2b = (v2f){0.f, 0.f};
            #pragma unroll
            for (int m = 0; m < 8; m += 2) {
                v2f s0 = xrv[m] + vv[m];
                v2f s1 = xrv[m+1] + vv[m+1];
                v2f a0 = __builtin_elementwise_max(s0, -s0);  // pk_max w/ neg
                v2f a1 = __builtin_elementwise_max(s1, -s1);
                e2a = __builtin_elementwise_fma(attv[m],   a0, e2a);
                e2b = __builtin_elementwise_fma(attv[m+1], a1, e2b);
            }
            v2f e2v = e2a + e2b;
            float e2h = e2v.x + e2v.y;
            float e = ebase[u] + dpp_xor1_add(e2h);   // both c-halves combined
            float w = masks[jj * TI + il] * __expf(e);
            sumw += w;
            v2f wv2 = (v2f){w, w};
            #pragma unroll
            for (int m = 0; m < 8; ++m)
                acc2[m] = __builtin_elementwise_fma(wv2, vv[m], acc2[m]);
        }
    }

    // sumw over the 8 q-lanes (bits 3-5); ch/il copies untouched.
    sumw += __shfl_xor(sumw, 8);
    sumw += __shfl_xor(sumw, 16);
    sumw += __shfl_xor(sumw, 32);
    const float inv = 1.f / sumw;

    float accf[16];
    #pragma unroll
    for (int m = 0; m < 8; ++m) { accf[2*m] = acc2[m].x; accf[2*m+1] = acc2[m].y; }

    // reduce-scatter over q: bit0 (xor 8), bit1 (xor 16), bit2 (xor 32).
    // lane keeps lower half if its bit==0, upper if bit==1.
    float r8[8];
    {
        const bool hi = (q & 1) != 0;
        #pragma unroll
        for (int m = 0; m < 8; ++m) {
            float send = hi ? accf[m] : accf[8 + m];
            float keep = hi ? accf[8 + m] : accf[m];
            r8[m] = keep + __shfl_xor(send, 8);
        }
    }
    float r4[4];
    {
        const bool hi = (q & 2) != 0;
        #pragma unroll
        for (int m = 0; m < 4; ++m) {
            float send = hi ? r8[m] : r8[4 + m];
            float keep = hi ? r8[4 + m] : r8[m];
            r4[m] = keep + __shfl_xor(send, 16);
        }
    }
    float r2[2];
    {
        const bool hi = (q & 4) != 0;
        #pragma unroll
        for (int m = 0; m < 2; ++m) {
            float send = hi ? r4[m] : r4[2 + m];
            float keep = hi ? r4[2 + m] : r4[m];
            r2[m] = keep + __shfl_xor(send, 32);
        }
    }

    const int off = (q & 1) * 8 + ((q >> 1) & 1) * 4 + ((q >> 2) & 1) * 2;
    const int c = cbase + off;
    float* op = out + ((size_t)(b * N_ + ig)) * OD;
    *(float2*)(&op[c]) = make_float2(fmaf(r2[0], inv, bias[c]),
                                     fmaf(r2[1], inv, bias[c + 1]));
}

extern "C" void kernel_launch(void* const* d_in, const int* in_sizes, int n_in,
                              void* d_out, int out_size, void* d_ws, size_t ws_size,
                              hipStream_t stream) {
    const float* x    = (const float*)d_in[0];
    const int*   adj  = (const int*)d_in[1];
    const float* Wl   = (const float*)d_in[2];
    const float* bl   = (const float*)d_in[3];
    const float* Wr   = (const float*)d_in[4];
    const float* br   = (const float*)d_in[5];
    const float* att  = (const float*)d_in[6];
    const float* bias = (const float*)d_in[7];
    float* out = (float*)d_out;

    float* xl = (float*)d_ws;                    // 2 MB
    float* xr = xl + (size_t)B_ * N_ * OD;       // 2 MB
    float* dl = xr + (size_t)B_ * N_ * OD;       // 64 KB
    float* dr = dl + (size_t)B_ * N_ * H_;       // 64 KB

    proj_kernel<<<512, 256, 0, stream>>>(x, Wl, bl, Wr, br, att, xl, xr, dl, dr);
    attn_kernel<<<1024, 256, 0, stream>>>(adj, att, bias, xl, xr, dl, dr, out);
}

// Round 7
// 128.718 us; speedup vs baseline: 1.2272x; 1.2272x over previous
//
#include <hip/hip_runtime.h>
#include <hip/hip_bf16.h>

#define B_   8
#define N_   512
#define IND  256
#define H_   4
#define PH   32
#define OD   128   // H_*PH
#define TI   4     // targets per block (attn)
#define TJ   64    // source tile (attn)
#define XLS_STRIDE 132  // 128 + 4 pad: phase-local bank spread (see r6 post-mortem)

typedef float v2f __attribute__((ext_vector_type(2)));

// leaky 0.4 * log2(e), and 0.6 * log2(e): logits computed in log2 domain.
#define ATT_SCALE 0.5770780163555854f
#define DLR_SCALE 0.8656170245333781f

__device__ __forceinline__ float dpp_xor1_add(float x) {
    // x + (lane^1).x via quad_perm(1,0,3,2): pure VALU, no LDS pipe.
    int yi = __builtin_amdgcn_mov_dpp(__float_as_int(x), 0xB1, 0xF, 0xF, true);
    return x + __int_as_float(yi);
}

__device__ __forceinline__ float fast_exp2(float x) {
#if __has_builtin(__builtin_amdgcn_exp2f)
    return __builtin_amdgcn_exp2f(x);
#else
    return exp2f(x);
#endif
}

// ---------------------------------------------------------------------------
// Kernel 1: xl = x@Wl + bl ; xr = x@Wr + br  plus pre-scaled rank-1 parts
//   dl[n,h] = 0.6*log2e * sum_c att[h,c]*xl[n,h,c]; dr likewise.
// grid 512, block 256; 8 rows per block. (structure proven r5/r6)
// ---------------------------------------------------------------------------
__global__ __launch_bounds__(256, 2) void proj_kernel(
    const float* __restrict__ x,
    const float* __restrict__ Wl, const float* __restrict__ bl,
    const float* __restrict__ Wr, const float* __restrict__ br,
    const float* __restrict__ att,
    float* __restrict__ xl, float* __restrict__ xr,
    float* __restrict__ dl, float* __restrict__ dr)
{
    __shared__ float xs[8 * IND];
    const int t = threadIdx.x;
    const int row0 = blockIdx.x * 8;

    const float4* xp4 = (const float4*)(x + (size_t)row0 * IND);
    float4* xs4 = (float4*)xs;
    #pragma unroll
    for (int k = 0; k < 2; ++k)
        xs4[t + k * 256] = xp4[t + k * 256];
    __syncthreads();

    const int which = t >> 7;
    const int rg = (t >> 6) & 1;
    const int og = t & 63;
    const int o0 = og * 2;
    const int r0 = rg * 4;
    const float* W  = which ? Wr : Wl;
    const float* bb = which ? br : bl;

    float acc0[4], acc1[4];
    #pragma unroll
    for (int r = 0; r < 4; ++r) { acc0[r] = 0.f; acc1[r] = 0.f; }

    for (int k = 0; k < IND; k += 4) {
        float wf0[4], wf1[4];
        #pragma unroll
        for (int kk = 0; kk < 4; ++kk) {
            float2 wv = *(const float2*)(W + (size_t)(k + kk) * OD + o0);
            wf0[kk] = wv.x;
            wf1[kk] = wv.y;
        }
        float xv[4][4];
        #pragma unroll
        for (int r = 0; r < 4; ++r)
            *(float4*)(xv[r]) = *(const float4*)(&xs[(r0 + r) * IND + k]);
        #pragma unroll
        for (int kk = 0; kk < 4; ++kk)
            #pragma unroll
            for (int r = 0; r < 4; ++r) {
                acc0[r] = fmaf(xv[r][kk], wf0[kk], acc0[r]);
                acc1[r] = fmaf(xv[r][kk], wf1[kk], acc1[r]);
            }
    }

    const float bv0 = bb[o0];
    const float bv1 = bb[o0 + 1];
    const float a0 = att[o0];
    const float a1 = att[o0 + 1];
    float* dst = which ? xr : xl;
    float* dp  = which ? dr : dl;
    float dcon[4];
    #pragma unroll
    for (int r = 0; r < 4; ++r) {
        float y0 = acc0[r] + bv0;
        float y1 = acc1[r] + bv1;
        *(float2*)(&dst[(size_t)(row0 + r0 + r) * OD + o0]) = make_float2(y0, y1);
        dcon[r] = fmaf(a0, y0, a1 * y1);
    }
    #pragma unroll
    for (int m = 1; m < 16; m <<= 1) {
        #pragma unroll
        for (int r = 0; r < 4; ++r)
            dcon[r] += __shfl_xor(dcon[r], m);
    }
    if ((og & 15) == 0) {
        const int h = og >> 4;
        #pragma unroll
        for (int r = 0; r < 4; ++r)
            dp[(size_t)(row0 + r0 + r) * H_ + h] = DLR_SCALE * dcon[r];
    }
}

// ---------------------------------------------------------------------------
// Kernel 2: masked-softmax attention aggregate.
// grid 1024 (= B*N/TI), block 256, LDS ~34.8 KB -> 4 blocks/CU.
// thread map (round-5, phase-bank-clean): ch = t&1, q = (t>>1)&7,
//   il = (t>>4)&3, h = t>>6.  Phase (8 consecutive lanes) = {ch, 4 q's}
//   -> 8 distinct bank groups at stride 132 -> conflict-free v-reads.
// Per-u pair-combine via DPP quad_perm (VALU) -- r5's ds_bpermute was the
// 4.2M-conflict in-chain stall. Packed v_pk_* fp32 math; logits in log2
// domain (att pre-scaled 0.4*log2e, dl/dr pre-scaled 0.6*log2e) -> single
// v_exp_f32 per edge. Masks preloaded to registers per tile (no in-chain
// LDS read). Softmax w/o max-subtraction (|e| <~ 10).
// ---------------------------------------------------------------------------
__global__ __launch_bounds__(256) void attn_kernel(
    const int* __restrict__ adj, const float* __restrict__ att,
    const float* __restrict__ bias,
    const float* __restrict__ xl, const float* __restrict__ xr,
    const float* __restrict__ dl, const float* __restrict__ dr,
    float* __restrict__ out)
{
    __shared__ float xls[TJ * XLS_STRIDE];  // 33.8 KB
    __shared__ float masks[TJ * TI];        // 1 KB   [jj][il]

    const int t = threadIdx.x;
    const int b  = blockIdx.x >> 7;
    const int i0 = (blockIdx.x & 127) * TI;
    const int ch = t & 1;
    const int q  = (t >> 1) & 7;
    const int il = (t >> 4) & 3;
    const int h  = t >> 6;
    const int ig = i0 + il;
    const int cbase = h * PH + ch * 16;

    v2f attv[8], xrv[8];
    {
        const float* xrp = xr + ((size_t)(b * N_ + ig)) * OD + cbase;
        const float* ap  = att + cbase;
        #pragma unroll
        for (int k = 0; k < 4; ++k) {
            float4 v = *(const float4*)(xrp + k * 4);
            xrv[2*k]   = (v2f){v.x, v.y};
            xrv[2*k+1] = (v2f){v.z, v.w};
            float4 a = *(const float4*)(ap + k * 4);
            attv[2*k]   = (v2f){ATT_SCALE * a.x, ATT_SCALE * a.y};
            attv[2*k+1] = (v2f){ATT_SCALE * a.z, ATT_SCALE * a.w};
        }
    }
    const float c0 = dr[((size_t)(b * N_ + ig)) * H_ + h];  // pre-scaled

    v2f acc2[8];
    #pragma unroll
    for (int m = 0; m < 8; ++m) acc2[m] = (v2f){0.f, 0.f};
    float sumw = 0.f;

    const float* xlb = xl + (size_t)b * N_ * OD;
    const int* adjb  = adj + (size_t)b * N_ * N_;

    for (int tile = 0; tile < N_ / TJ; ++tile) {
        const int j0 = tile * TJ;
        __syncthreads();
        // stage xl tile: 64 rows x 128 fp32, padded stride (phase-clean)
        #pragma unroll
        for (int k = 0; k < 8; ++k) {
            int idx = t + k * 256;          // float4 units, 0..2047
            int jj = idx >> 5, m = idx & 31;
            *(float4*)(&xls[jj * XLS_STRIDE + m * 4]) =
                *(const float4*)(xlb + (size_t)(j0 + jj) * OD + m * 4);
        }
        // adjacency mask: m[i,j] = adj[b][j][i] != 0, diagonal forced 1
        {
            int jj = t >> 2, ii = t & 3;
            int jg2 = j0 + jj, ig2 = i0 + ii;
            int a = adjb[(size_t)jg2 * N_ + ig2];
            masks[t] = (a != 0 || jg2 == ig2) ? 1.f : 0.f;
        }
        __syncthreads();

        // per-u logit bases (pre-scaled dl, L2-hot) and register masks:
        // independent loads, issued before the chain so latency is hidden.
        const float* dlt = dl + ((size_t)b * N_ + j0) * H_ + h;
        float ebase[8], mreg[8];
        #pragma unroll
        for (int u = 0; u < 8; ++u) {
            ebase[u] = dlt[(q + u * 8) * H_] + c0;
            mreg[u]  = masks[(q + u * 8) * TI + il];
        }

        #pragma unroll
        for (int u = 0; u < 8; ++u) {
            const int jj = q + u * 8;
            const float* vrow = &xls[jj * XLS_STRIDE + cbase];
            float4 f0 = *(const float4*)(vrow + 0);
            float4 f1 = *(const float4*)(vrow + 4);
            float4 f2 = *(const float4*)(vrow + 8);
            float4 f3 = *(const float4*)(vrow + 12);
            v2f vv[8] = {{f0.x,f0.y},{f0.z,f0.w},{f1.x,f1.y},{f1.z,f1.w},
                         {f2.x,f2.y},{f2.z,f2.w},{f3.x,f3.y},{f3.z,f3.w}};
            v2f e2a = (v2f){0.f, 0.f}, e2b = (v2f){0.f, 0.f};
            #pragma unroll
            for (int m = 0; m < 8; m += 2) {
                v2f s0 = xrv[m] + vv[m];
                v2f s1 = xrv[m+1] + vv[m+1];
                v2f a0 = __builtin_elementwise_max(s0, -s0);  // pk_max w/ neg
                v2f a1 = __builtin_elementwise_max(s1, -s1);
                e2a = __builtin_elementwise_fma(attv[m],   a0, e2a);
                e2b = __builtin_elementwise_fma(attv[m+1], a1, e2b);
            }
            v2f e2v = e2a + e2b;
            float e2h = e2v.x + e2v.y;
            float e = ebase[u] + dpp_xor1_add(e2h);   // both c-halves
            float w = mreg[u] * fast_exp2(e);
            sumw += w;
            v2f wv2 = (v2f){w, w};
            #pragma unroll
            for (int m = 0; m < 8; ++m)
                acc2[m] = __builtin_elementwise_fma(wv2, vv[m], acc2[m]);
        }
    }

    // sumw over the 8 q-lanes (lane bits 1-3); ch/il copies untouched.
    sumw += __shfl_xor(sumw, 2);
    sumw += __shfl_xor(sumw, 4);
    sumw += __shfl_xor(sumw, 8);
    const float inv = 1.f / sumw;

    float accf[16];
    #pragma unroll
    for (int m = 0; m < 8; ++m) { accf[2*m] = acc2[m].x; accf[2*m+1] = acc2[m].y; }

    // acc: 3-level reduce-scatter over q (r5-proven); lane ends with
    // c = cbase + 2q.
    float r8[8];
    {
        const bool hi = (q & 4) != 0;
        #pragma unroll
        for (int m = 0; m < 8; ++m) {
            float send = hi ? accf[m] : accf[8 + m];
            float keep = hi ? accf[8 + m] : accf[m];
            r8[m] = keep + __shfl_xor(send, 8);
        }
    }
    float r4[4];
    {
        const bool hi = (q & 2) != 0;
        #pragma unroll
        for (int m = 0; m < 4; ++m) {
            float send = hi ? r8[m] : r8[4 + m];
            float keep = hi ? r8[4 + m] : r8[m];
            r4[m] = keep + __shfl_xor(send, 4);
        }
    }
    float r2[2];
    {
        const bool hi = (q & 1) != 0;
        #pragma unroll
        for (int m = 0; m < 2; ++m) {
            float send = hi ? r4[m] : r4[2 + m];
            float keep = hi ? r4[2 + m] : r4[m];
            r2[m] = keep + __shfl_xor(send, 2);
        }
    }

    const int c = cbase + q * 2;
    float* op = out + ((size_t)(b * N_ + ig)) * OD;
    *(float2*)(&op[c]) = make_float2(fmaf(r2[0], inv, bias[c]),
                                     fmaf(r2[1], inv, bias[c + 1]));
}

extern "C" void kernel_launch(void* const* d_in, const int* in_sizes, int n_in,
                              void* d_out, int out_size, void* d_ws, size_t ws_size,
                              hipStream_t stream) {
    const float* x    = (const float*)d_in[0];
    const int*   adj  = (const int*)d_in[1];
    const float* Wl   = (const float*)d_in[2];
    const float* bl   = (const float*)d_in[3];
    const float* Wr   = (const float*)d_in[4];
    const float* br   = (const float*)d_in[5];
    const float* att  = (const float*)d_in[6];
    const float* bias = (const float*)d_in[7];
    float* out = (float*)d_out;

    float* xl = (float*)d_ws;                    // 2 MB
    float* xr = xl + (size_t)B_ * N_ * OD;       // 2 MB
    float* dl = xr + (size_t)B_ * N_ * OD;       // 64 KB
    float* dr = dl + (size_t)B_ * N_ * H_;       // 64 KB

    proj_kernel<<<512, 256, 0, stream>>>(x, Wl, bl, Wr, br, att, xl, xr, dl, dr);
    attn_kernel<<<1024, 256, 0, stream>>>(adj, att, bias, xl, xr, dl, dr, out);
}

// Round 9
// 125.162 us; speedup vs baseline: 1.2620x; 1.0284x over previous
//
#include <hip/hip_runtime.h>
#include <hip/hip_bf16.h>

#define B_   8
#define N_   512
#define IND  256
#define H_   4
#define PH   32
#define OD   128   // H_*PH
#define TI   4     // targets per block (attn)

typedef float v2f __attribute__((ext_vector_type(2)));

// leaky 0.4 * log2(e), and 0.6 * log2(e): logits in log2 domain -> v_exp_f32.
#define ATT_SCALE 0.5770780163555854f
#define DLR_SCALE 0.8656170245333781f

template <int PAT>
__device__ __forceinline__ float dpp_add(float x) {
    // DPP ctrl must be an immediate -> template parameter.
    int yi = __builtin_amdgcn_mov_dpp(__float_as_int(x), PAT, 0xF, 0xF, true);
    return x + __int_as_float(yi);
}

__device__ __forceinline__ float fast_exp2(float x) {
#if __has_builtin(__builtin_amdgcn_exp2f)
    return __builtin_amdgcn_exp2f(x);
#else
    return exp2f(x);
#endif
}

// ---------------------------------------------------------------------------
// Kernel 1: xl = x@Wl + bl ; xr = x@Wr + br  plus pre-scaled rank-1 parts
//   dl[n,h] = 0.6*log2e * sum_c att[h,c]*xl[n,h,c]; dr likewise.
// grid 512, block 256; 8 rows per block. (unchanged, proven r5-r7)
// ---------------------------------------------------------------------------
__global__ __launch_bounds__(256, 2) void proj_kernel(
    const float* __restrict__ x,
    const float* __restrict__ Wl, const float* __restrict__ bl,
    const float* __restrict__ Wr, const float* __restrict__ br,
    const float* __restrict__ att,
    float* __restrict__ xl, float* __restrict__ xr,
    float* __restrict__ dl, float* __restrict__ dr)
{
    __shared__ float xs[8 * IND];
    const int t = threadIdx.x;
    const int row0 = blockIdx.x * 8;

    const float4* xp4 = (const float4*)(x + (size_t)row0 * IND);
    float4* xs4 = (float4*)xs;
    #pragma unroll
    for (int k = 0; k < 2; ++k)
        xs4[t + k * 256] = xp4[t + k * 256];
    __syncthreads();

    const int which = t >> 7;
    const int rg = (t >> 6) & 1;
    const int og = t & 63;
    const int o0 = og * 2;
    const int r0 = rg * 4;
    const float* W  = which ? Wr : Wl;
    const float* bb = which ? br : bl;

    float acc0[4], acc1[4];
    #pragma unroll
    for (int r = 0; r < 4; ++r) { acc0[r] = 0.f; acc1[r] = 0.f; }

    for (int k = 0; k < IND; k += 4) {
        float wf0[4], wf1[4];
        #pragma unroll
        for (int kk = 0; kk < 4; ++kk) {
            float2 wv = *(const float2*)(W + (size_t)(k + kk) * OD + o0);
            wf0[kk] = wv.x;
            wf1[kk] = wv.y;
        }
        float xv[4][4];
        #pragma unroll
        for (int r = 0; r < 4; ++r)
            *(float4*)(xv[r]) = *(const float4*)(&xs[(r0 + r) * IND + k]);
        #pragma unroll
        for (int kk = 0; kk < 4; ++kk)
            #pragma unroll
            for (int r = 0; r < 4; ++r) {
                acc0[r] = fmaf(xv[r][kk], wf0[kk], acc0[r]);
                acc1[r] = fmaf(xv[r][kk], wf1[kk], acc1[r]);
            }
    }

    const float bv0 = bb[o0];
    const float bv1 = bb[o0 + 1];
    const float a0 = att[o0];
    const float a1 = att[o0 + 1];
    float* dst = which ? xr : xl;
    float* dp  = which ? dr : dl;
    float dcon[4];
    #pragma unroll
    for (int r = 0; r < 4; ++r) {
        float y0 = acc0[r] + bv0;
        float y1 = acc1[r] + bv1;
        *(float2*)(&dst[(size_t)(row0 + r0 + r) * OD + o0]) = make_float2(y0, y1);
        dcon[r] = fmaf(a0, y0, a1 * y1);
    }
    #pragma unroll
    for (int m = 1; m < 16; m <<= 1) {
        #pragma unroll
        for (int r = 0; r < 4; ++r)
            dcon[r] += __shfl_xor(dcon[r], m);
    }
    if ((og & 15) == 0) {
        const int h = og >> 4;
        #pragma unroll
        for (int r = 0; r < 4; ++r)
            dp[(size_t)(row0 + r0 + r) * H_ + h] = DLR_SCALE * dcon[r];
    }
}

// ---------------------------------------------------------------------------
// Kernel 2: masked-softmax attention aggregate. NO LDS / NO BARRIER main loop.
// grid 1024 (= B*N/TI), block 256.
// thread: cq = t&3 (c-quarter, 8 ch), js = (t>>2)&15 (16 j-slices), h = t>>6.
// Each thread reads each xl slice ONCE from global (L2-hot; per-block
// footprint = xl[b] exactly once) and computes all TI=4 targets in registers
// -- r7 post-mortem: the old 4x LDS read redundancy + the structural 4-cyc
// ds_read_b128 conflict made LDS+VALU jointly ~42% busy / latency-bound.
// e2 combined across the 4 cq lanes with two DPP quad-perm adds (pure VALU).
// Epilogue: one-time 33 KB LDS transpose + js-reduction.
// ---------------------------------------------------------------------------
__global__ __launch_bounds__(256, 3) void attn_kernel(
    const int* __restrict__ adj, const float* __restrict__ att,
    const float* __restrict__ bias,
    const float* __restrict__ xl, const float* __restrict__ xr,
    const float* __restrict__ dl, const float* __restrict__ dr,
    float* __restrict__ out)
{
    __shared__ float sacc[H_][16][TI][PH];  // [h][js][il][c] 32 KB
    __shared__ float ssum[H_][16][TI];      // 1 KB

    const int t = threadIdx.x;
    const int b  = blockIdx.x >> 7;
    const int i0 = (blockIdx.x & 127) * TI;
    const int cq = t & 3;
    const int js = (t >> 2) & 15;
    const int h  = t >> 6;
    const int cbase = h * PH + cq * 8;

    // preload att (pre-scaled by 0.4*log2e) and xr fragments for all 4 targets
    v2f attv[4];
    {
        const float* ap = att + cbase;
        float4 a0 = *(const float4*)(ap);
        float4 a1 = *(const float4*)(ap + 4);
        attv[0] = (v2f){ATT_SCALE * a0.x, ATT_SCALE * a0.y};
        attv[1] = (v2f){ATT_SCALE * a0.z, ATT_SCALE * a0.w};
        attv[2] = (v2f){ATT_SCALE * a1.x, ATT_SCALE * a1.y};
        attv[3] = (v2f){ATT_SCALE * a1.z, ATT_SCALE * a1.w};
    }
    v2f xrv[TI][4];
    float drv[TI];
    #pragma unroll
    for (int il = 0; il < TI; ++il) {
        const float* xp = xr + ((size_t)(b * N_ + i0 + il)) * OD + cbase;
        float4 r0 = *(const float4*)(xp);
        float4 r1 = *(const float4*)(xp + 4);
        xrv[il][0] = (v2f){r0.x, r0.y};
        xrv[il][1] = (v2f){r0.z, r0.w};
        xrv[il][2] = (v2f){r1.x, r1.y};
        xrv[il][3] = (v2f){r1.z, r1.w};
        drv[il] = dr[((size_t)(b * N_ + i0 + il)) * H_ + h];  // pre-scaled
    }

    v2f acc[TI][4];
    float sumw[TI];
    #pragma unroll
    for (int il = 0; il < TI; ++il) {
        sumw[il] = 0.f;
        #pragma unroll
        for (int m = 0; m < 4; ++m) acc[il][m] = (v2f){0.f, 0.f};
    }

    // software-pipelined j-loop: j = u*16 + js, u = 0..31
    const float* xlp = xl + ((size_t)(b * N_ + js)) * OD + cbase;
    const int*   ajp = adj + ((size_t)(b * N_ + js)) * N_ + i0;
    const float* dlp = dl + ((size_t)(b * N_ + js)) * H_ + h;

    float4 va = *(const float4*)(xlp);
    float4 vb = *(const float4*)(xlp + 4);
    int4   mj = *(const int4*)(ajp);
    float  dj = *dlp;

    #pragma unroll 2
    for (int u = 0; u < 32; ++u) {
        float4 wa = va, wb = vb;
        int4   wm = mj;
        float  wd = dj;
        if (u < 31) {
            xlp += 16 * OD; ajp += 16 * N_; dlp += 16 * H_;
            va = *(const float4*)(xlp);
            vb = *(const float4*)(xlp + 4);
            mj = *(const int4*)(ajp);
            dj = *dlp;
        }
        const int j = u * 16 + js;
        v2f v0 = (v2f){wa.x, wa.y}, v1 = (v2f){wa.z, wa.w};
        v2f v2 = (v2f){wb.x, wb.y}, v3 = (v2f){wb.z, wb.w};
        int wmv[4] = {wm.x, wm.y, wm.z, wm.w};
        #pragma unroll
        for (int il = 0; il < TI; ++il) {
            v2f s, e0 = (v2f){0.f, 0.f}, e1 = (v2f){0.f, 0.f};
            s = xrv[il][0] + v0; s = __builtin_elementwise_max(s, -s);
            e0 = __builtin_elementwise_fma(attv[0], s, e0);
            s = xrv[il][1] + v1; s = __builtin_elementwise_max(s, -s);
            e1 = __builtin_elementwise_fma(attv[1], s, e1);
            s = xrv[il][2] + v2; s = __builtin_elementwise_max(s, -s);
            e0 = __builtin_elementwise_fma(attv[2], s, e0);
            s = xrv[il][3] + v3; s = __builtin_elementwise_max(s, -s);
            e1 = __builtin_elementwise_fma(attv[3], s, e1);
            v2f et = e0 + e1;
            float eh = et.x + et.y;          // this cq's partial
            eh = dpp_add<0xB1>(eh);          // + lane^1  (quad_perm 1,0,3,2)
            eh = dpp_add<0x4E>(eh);          // + lane^2  (quad_perm 2,3,0,1)
            float e = (wd + drv[il]) + eh;   // full log2-domain logit
            bool keep = (wmv[il] != 0) || (j == i0 + il);
            float w = keep ? fast_exp2(e) : 0.f;
            sumw[il] += w;
            v2f wv2 = (v2f){w, w};
            acc[il][0] = __builtin_elementwise_fma(wv2, v0, acc[il][0]);
            acc[il][1] = __builtin_elementwise_fma(wv2, v1, acc[il][1]);
            acc[il][2] = __builtin_elementwise_fma(wv2, v2, acc[il][2]);
            acc[il][3] = __builtin_elementwise_fma(wv2, v3, acc[il][3]);
        }
    }

    // ---- epilogue: LDS transpose + reduce over the 16 js slices ----
    #pragma unroll
    for (int il = 0; il < TI; ++il) {
        float4 w0 = make_float4(acc[il][0].x, acc[il][0].y,
                                acc[il][1].x, acc[il][1].y);
        float4 w1 = make_float4(acc[il][2].x, acc[il][2].y,
                                acc[il][3].x, acc[il][3].y);
        *(float4*)(&sacc[h][js][il][cq * 8])     = w0;
        *(float4*)(&sacc[h][js][il][cq * 8 + 4]) = w1;
    }
    if (cq == 0) {
        #pragma unroll
        for (int il = 0; il < TI; ++il)
            ssum[h][js][il] = sumw[il];
    }
    __syncthreads();

    const int lane = t & 63;
    const int o = lane * 2;          // output pair within this head
    const int il2 = o >> 5;          // 0..3
    const int c2 = o & 31;           // 0..30 even
    float st = 0.f;
    #pragma unroll
    for (int k = 0; k < 16; ++k) st += ssum[h][k][il2];
    float a0 = 0.f, a1 = 0.f;
    #pragma unroll
    for (int k = 0; k < 16; ++k) {
        float2 p = *(const float2*)(&sacc[h][k][il2][c2]);
        a0 += p.x; a1 += p.y;
    }
    const float inv = 1.f / st;
    const int c = h * PH + c2;
    float* op = out + ((size_t)(b * N_ + i0 + il2)) * OD;
    *(float2*)(&op[c]) = make_float2(fmaf(a0, inv, bias[c]),
                                     fmaf(a1, inv, bias[c + 1]));
}

extern "C" void kernel_launch(void* const* d_in, const int* in_sizes, int n_in,
                              void* d_out, int out_size, void* d_ws, size_t ws_size,
                              hipStream_t stream) {
    const float* x    = (const float*)d_in[0];
    const int*   adj  = (const int*)d_in[1];
    const float* Wl   = (const float*)d_in[2];
    const float* bl   = (const float*)d_in[3];
    const float* Wr   = (const float*)d_in[4];
    const float* br   = (const float*)d_in[5];
    const float* att  = (const float*)d_in[6];
    const float* bias = (const float*)d_in[7];
    float* out = (float*)d_out;

    float* xl = (float*)d_ws;                    // 2 MB
    float* xr = xl + (size_t)B_ * N_ * OD;       // 2 MB
    float* dl = xr + (size_t)B_ * N_ * OD;       // 64 KB
    float* dr = dl + (size_t)B_ * N_ * H_;       // 64 KB

    proj_kernel<<<512, 256, 0, stream>>>(x, Wl, bl, Wr, br, att, xl, xr, dl, dr);
    attn_kernel<<<1024, 256, 0, stream>>>(adj, att, bias, xl, xr, dl, dr, out);
}

// Round 10
// 121.157 us; speedup vs baseline: 1.3038x; 1.0331x over previous
//
#include <hip/hip_runtime.h>
#include <hip/hip_bf16.h>

#define B_   8
#define N_   512
#define IND  256
#define H_   4
#define PH   32
#define OD   128   // H_*PH
#define TI   4     // targets per block (attn)

typedef float v2f __attribute__((ext_vector_type(2)));

// leaky 0.4 * log2(e), and 0.6 * log2(e): logits in log2 domain -> v_exp_f32.
#define ATT_SCALE 0.5770780163555854f
#define DLR_SCALE 0.8656170245333781f

template <int PAT>
__device__ __forceinline__ float dpp_add(float x) {
    int yi = __builtin_amdgcn_mov_dpp(__float_as_int(x), PAT, 0xF, 0xF, true);
    return x + __int_as_float(yi);
}

__device__ __forceinline__ float fast_exp2(float x) {
#if __has_builtin(__builtin_amdgcn_exp2f)
    return __builtin_amdgcn_exp2f(x);
#else
    return exp2f(x);
#endif
}

// Packed fp32 FMA: d += a*b on both halves, ONE VOP3P instruction.
// (No modifiers needed on this path, so packing is legal here; the e2 path
// must stay scalar because VOP3P has no abs modifier -- r9 post-mortem.)
__device__ __forceinline__ void pk_fma(v2f& d, v2f a, v2f b) {
    asm("v_pk_fma_f32 %0, %1, %2, %0" : "+v"(d) : "v"(a), "v"(b));
}

// ---------------------------------------------------------------------------
// Kernel 1: xl = x@Wl + bl ; xr = x@Wr + br  plus pre-scaled rank-1 parts
//   dl[n,h] = 0.6*log2e * sum_c att[h,c]*xl[n,h,c]; dr likewise.
// grid 512, block 256; 8 rows per block. (unchanged, proven r5-r9)
// ---------------------------------------------------------------------------
__global__ __launch_bounds__(256, 2) void proj_kernel(
    const float* __restrict__ x,
    const float* __restrict__ Wl, const float* __restrict__ bl,
    const float* __restrict__ Wr, const float* __restrict__ br,
    const float* __restrict__ att,
    float* __restrict__ xl, float* __restrict__ xr,
    float* __restrict__ dl, float* __restrict__ dr)
{
    __shared__ float xs[8 * IND];
    const int t = threadIdx.x;
    const int row0 = blockIdx.x * 8;

    const float4* xp4 = (const float4*)(x + (size_t)row0 * IND);
    float4* xs4 = (float4*)xs;
    #pragma unroll
    for (int k = 0; k < 2; ++k)
        xs4[t + k * 256] = xp4[t + k * 256];
    __syncthreads();

    const int which = t >> 7;
    const int rg = (t >> 6) & 1;
    const int og = t & 63;
    const int o0 = og * 2;
    const int r0 = rg * 4;
    const float* W  = which ? Wr : Wl;
    const float* bb = which ? br : bl;

    float acc0[4], acc1[4];
    #pragma unroll
    for (int r = 0; r < 4; ++r) { acc0[r] = 0.f; acc1[r] = 0.f; }

    for (int k = 0; k < IND; k += 4) {
        float wf0[4], wf1[4];
        #pragma unroll
        for (int kk = 0; kk < 4; ++kk) {
            float2 wv = *(const float2*)(W + (size_t)(k + kk) * OD + o0);
            wf0[kk] = wv.x;
            wf1[kk] = wv.y;
        }
        float xv[4][4];
        #pragma unroll
        for (int r = 0; r < 4; ++r)
            *(float4*)(xv[r]) = *(const float4*)(&xs[(r0 + r) * IND + k]);
        #pragma unroll
        for (int kk = 0; kk < 4; ++kk)
            #pragma unroll
            for (int r = 0; r < 4; ++r) {
                acc0[r] = fmaf(xv[r][kk], wf0[kk], acc0[r]);
                acc1[r] = fmaf(xv[r][kk], wf1[kk], acc1[r]);
            }
    }

    const float bv0 = bb[o0];
    const float bv1 = bb[o0 + 1];
    const float a0 = att[o0];
    const float a1 = att[o0 + 1];
    float* dst = which ? xr : xl;
    float* dp  = which ? dr : dl;
    float dcon[4];
    #pragma unroll
    for (int r = 0; r < 4; ++r) {
        float y0 = acc0[r] + bv0;
        float y1 = acc1[r] + bv1;
        *(float2*)(&dst[(size_t)(row0 + r0 + r) * OD + o0]) = make_float2(y0, y1);
        dcon[r] = fmaf(a0, y0, a1 * y1);
    }
    #pragma unroll
    for (int m = 1; m < 16; m <<= 1) {
        #pragma unroll
        for (int r = 0; r < 4; ++r)
            dcon[r] += __shfl_xor(dcon[r], m);
    }
    if ((og & 15) == 0) {
        const int h = og >> 4;
        #pragma unroll
        for (int r = 0; r < 4; ++r)
            dp[(size_t)(row0 + r0 + r) * H_ + h] = DLR_SCALE * dcon[r];
    }
}

// ---------------------------------------------------------------------------
// Kernel 2: masked-softmax attention aggregate. NO LDS / NO BARRIER main loop.
// grid 1024 (= B*N/TI), block 256.
// thread: cq = t&3 (c-quarter, 8 ch), js = (t>>2)&15 (16 j-slices), h = t>>6.
// e2 path: SCALAR add + fma(abs-modifier folded, free) = 2 instr/elem -- the
// minimal form (r9 post-mortem: v2f max(s,-s) scalarized to 3/elem because
// VOP3P lacks abs modifiers / pk_max_f32). PV path: forced v_pk_fma_f32.
// e2 combined across the 4 cq lanes with two DPP quad-perm adds (pure VALU).
// Epilogue: one-time 33 KB LDS transpose + js-reduction.
// ---------------------------------------------------------------------------
__global__ __launch_bounds__(256, 3) void attn_kernel(
    const int* __restrict__ adj, const float* __restrict__ att,
    const float* __restrict__ bias,
    const float* __restrict__ xl, const float* __restrict__ xr,
    const float* __restrict__ dl, const float* __restrict__ dr,
    float* __restrict__ out)
{
    __shared__ float sacc[H_][16][TI][PH];  // [h][js][il][c] 32 KB
    __shared__ float ssum[H_][16][TI];      // 1 KB

    const int t = threadIdx.x;
    const int b  = blockIdx.x >> 7;
    const int i0 = (blockIdx.x & 127) * TI;
    const int cq = t & 3;
    const int js = (t >> 2) & 15;
    const int h  = t >> 6;
    const int cbase = h * PH + cq * 8;

    // preload att (pre-scaled by 0.4*log2e) and xr fragments for all 4 targets
    float atS[8];
    {
        const float* ap = att + cbase;
        float4 a0 = *(const float4*)(ap);
        float4 a1 = *(const float4*)(ap + 4);
        atS[0] = ATT_SCALE * a0.x; atS[1] = ATT_SCALE * a0.y;
        atS[2] = ATT_SCALE * a0.z; atS[3] = ATT_SCALE * a0.w;
        atS[4] = ATT_SCALE * a1.x; atS[5] = ATT_SCALE * a1.y;
        atS[6] = ATT_SCALE * a1.z; atS[7] = ATT_SCALE * a1.w;
    }
    float xrS[TI][8];
    float drv[TI];
    #pragma unroll
    for (int il = 0; il < TI; ++il) {
        const float* xp = xr + ((size_t)(b * N_ + i0 + il)) * OD + cbase;
        float4 r0 = *(const float4*)(xp);
        float4 r1 = *(const float4*)(xp + 4);
        xrS[il][0] = r0.x; xrS[il][1] = r0.y; xrS[il][2] = r0.z; xrS[il][3] = r0.w;
        xrS[il][4] = r1.x; xrS[il][5] = r1.y; xrS[il][6] = r1.z; xrS[il][7] = r1.w;
        drv[il] = dr[((size_t)(b * N_ + i0 + il)) * H_ + h];  // pre-scaled
    }

    v2f acc[TI][4];
    float sumw[TI];
    #pragma unroll
    for (int il = 0; il < TI; ++il) {
        sumw[il] = 0.f;
        #pragma unroll
        for (int m = 0; m < 4; ++m) acc[il][m] = (v2f){0.f, 0.f};
    }

    // software-pipelined j-loop: j = u*16 + js, u = 0..31
    const float* xlp = xl + ((size_t)(b * N_ + js)) * OD + cbase;
    const int*   ajp = adj + ((size_t)(b * N_ + js)) * N_ + i0;
    const float* dlp = dl + ((size_t)(b * N_ + js)) * H_ + h;

    float4 va = *(const float4*)(xlp);
    float4 vb = *(const float4*)(xlp + 4);
    int4   mj = *(const int4*)(ajp);
    float  dj = *dlp;

    #pragma unroll 2
    for (int u = 0; u < 32; ++u) {
        float4 wa = va, wb = vb;
        int4   wm = mj;
        float  wd = dj;
        if (u < 31) {
            xlp += 16 * OD; ajp += 16 * N_; dlp += 16 * H_;
            va = *(const float4*)(xlp);
            vb = *(const float4*)(xlp + 4);
            mj = *(const int4*)(ajp);
            dj = *dlp;
        }
        const int j = u * 16 + js;
        v2f p0 = (v2f){wa.x, wa.y}, p1 = (v2f){wa.z, wa.w};
        v2f p2 = (v2f){wb.x, wb.y}, p3 = (v2f){wb.z, wb.w};
        int wmv[4] = {wm.x, wm.y, wm.z, wm.w};
        #pragma unroll
        for (int il = 0; il < TI; ++il) {
            float s, e2a = 0.f, e2b = 0.f;
            s = xrS[il][0] + wa.x; e2a = fmaf(atS[0], __builtin_fabsf(s), e2a);
            s = xrS[il][1] + wa.y; e2b = fmaf(atS[1], __builtin_fabsf(s), e2b);
            s = xrS[il][2] + wa.z; e2a = fmaf(atS[2], __builtin_fabsf(s), e2a);
            s = xrS[il][3] + wa.w; e2b = fmaf(atS[3], __builtin_fabsf(s), e2b);
            s = xrS[il][4] + wb.x; e2a = fmaf(atS[4], __builtin_fabsf(s), e2a);
            s = xrS[il][5] + wb.y; e2b = fmaf(atS[5], __builtin_fabsf(s), e2b);
            s = xrS[il][6] + wb.z; e2a = fmaf(atS[6], __builtin_fabsf(s), e2a);
            s = xrS[il][7] + wb.w; e2b = fmaf(atS[7], __builtin_fabsf(s), e2b);
            float eh = e2a + e2b;
            eh = dpp_add<0xB1>(eh);          // + lane^1 (quad_perm 1,0,3,2)
            eh = dpp_add<0x4E>(eh);          // + lane^2 (quad_perm 2,3,0,1)
            float e = (wd + drv[il]) + eh;   // full log2-domain logit
            bool keep = (wmv[il] != 0) || (j == i0 + il);
            float w = keep ? fast_exp2(e) : 0.f;
            sumw[il] += w;
            v2f ws = (v2f){w, w};
            pk_fma(acc[il][0], ws, p0);
            pk_fma(acc[il][1], ws, p1);
            pk_fma(acc[il][2], ws, p2);
            pk_fma(acc[il][3], ws, p3);
        }
    }

    // ---- epilogue: LDS transpose + reduce over the 16 js slices ----
    #pragma unroll
    for (int il = 0; il < TI; ++il) {
        float4 w0 = make_float4(acc[il][0].x, acc[il][0].y,
                                acc[il][1].x, acc[il][1].y);
        float4 w1 = make_float4(acc[il][2].x, acc[il][2].y,
                                acc[il][3].x, acc[il][3].y);
        *(float4*)(&sacc[h][js][il][cq * 8])     = w0;
        *(float4*)(&sacc[h][js][il][cq * 8 + 4]) = w1;
    }
    if (cq == 0) {
        #pragma unroll
        for (int il = 0; il < TI; ++il)
            ssum[h][js][il] = sumw[il];
    }
    __syncthreads();

    const int lane = t & 63;
    const int o = lane * 2;          // output pair within this head
    const int il2 = o >> 5;          // 0..3
    const int c2 = o & 31;           // 0..30 even
    float st = 0.f;
    #pragma unroll
    for (int k = 0; k < 16; ++k) st += ssum[h][k][il2];
    float a0 = 0.f, a1 = 0.f;
    #pragma unroll
    for (int k = 0; k < 16; ++k) {
        float2 p = *(const float2*)(&sacc[h][k][il2][c2]);
        a0 += p.x; a1 += p.y;
    }
    const float inv = 1.f / st;
    const int c = h * PH + c2;
    float* op = out + ((size_t)(b * N_ + i0 + il2)) * OD;
    *(float2*)(&op[c]) = make_float2(fmaf(a0, inv, bias[c]),
                                     fmaf(a1, inv, bias[c + 1]));
}

extern "C" void kernel_launch(void* const* d_in, const int* in_sizes, int n_in,
                              void* d_out, int out_size, void* d_ws, size_t ws_size,
                              hipStream_t stream) {
    const float* x    = (const float*)d_in[0];
    const int*   adj  = (const int*)d_in[1];
    const float* Wl   = (const float*)d_in[2];
    const float* bl   = (const float*)d_in[3];
    const float* Wr   = (const float*)d_in[4];
    const float* br   = (const float*)d_in[5];
    const float* att  = (const float*)d_in[6];
    const float* bias = (const float*)d_in[7];
    float* out = (float*)d_out;

    float* xl = (float*)d_ws;                    // 2 MB
    float* xr = xl + (size_t)B_ * N_ * OD;       // 2 MB
    float* dl = xr + (size_t)B_ * N_ * OD;       // 64 KB
    float* dr = dl + (size_t)B_ * N_ * H_;       // 64 KB

    proj_kernel<<<512, 256, 0, stream>>>(x, Wl, bl, Wr, br, att, xl, xr, dl, dr);
    attn_kernel<<<1024, 256, 0, stream>>>(adj, att, bias, xl, xr, dl, dr, out);
}